// Round 4
// baseline (1135.070 us; speedup 1.0000x reference)
//
#include <hip/hip_runtime.h>

// GatingMixedDecoder: B=4096, LATENT=768, COND=512, INPUT=1280, HIDDEN=1024,
// OUT=512, E=8, GATE_H=512, INTER=1792.
// fp16 MFMA (16x16x32) for all GEMMs, fp32 elsewhere.
// R4: split-K x4 (4 blocks/CU; VGPR=128 is exactly the 4-waves/SIMD boundary),
//     f16 partial buffers (P0..P3 fit the 33.5 MB union region, halve P traffic).
//     Keeps R3's XOR-swizzled LDS + LN-fused combine.

typedef _Float16 f16;
typedef _Float16 f16x8 __attribute__((ext_vector_type(8)));
typedef _Float16 f16x4 __attribute__((ext_vector_type(4)));
typedef float    f32x4 __attribute__((ext_vector_type(4)));

typedef __attribute__((address_space(1))) void as1_void;
typedef __attribute__((address_space(3))) void as3_void;

__device__ __forceinline__ void gload_lds16(const void* g, void* l) {
  __builtin_amdgcn_global_load_lds((as1_void*)g, (as3_void*)l, 16, 0, 0);
}

__device__ __forceinline__ float leaky(float v) { return v > 0.f ? v : 0.01f * v; }

// ---------------- transpose + cast f32 -> f16 ----------------
// in: [batch, R, C] f32 ; out: [batch, C, R] f16. grid (C/32, R/32, batch), block (32,8)
__global__ __launch_bounds__(256) void transpose_cast(const float* __restrict__ in,
                                                      f16* __restrict__ out,
                                                      int R, int C) {
  __shared__ float tile[32][33];
  const size_t mat = (size_t)R * C;
  const float* I = in + mat * blockIdx.z;
  f16* O = out + mat * blockIdx.z;
  const int c0 = blockIdx.x * 32, r0 = blockIdx.y * 32;
  const int tx = threadIdx.x, ty = threadIdx.y;
#pragma unroll
  for (int i = ty; i < 32; i += 8)
    tile[i][tx] = I[(size_t)(r0 + i) * C + (c0 + tx)];
  __syncthreads();
#pragma unroll
  for (int i = ty; i < 32; i += 8)
    O[(size_t)(c0 + i) * R + (r0 + tx)] = (f16)tile[tx][i];
}

// ---------------- LN0 over concat(z[768], c[512]) -> fp16 Xh; raw fp16 -> zc_h ----
// D=1280 -> 320 float4 chunks. tid handles chunk tid; tid<64 also chunk tid+256.
__global__ __launch_bounds__(256) void ln0_kernel(
    const float* __restrict__ z, const float* __restrict__ prev,
    const float* __restrict__ gam, const float* __restrict__ bet,
    f16* __restrict__ Xh, f16* __restrict__ raw) {
  constexpr int DP = 512, D = 768 + DP, NCH = D / 4;  // 320
  constexpr float invD = 1.f / (float)D;
  const int row = blockIdx.x, tid = threadIdx.x;
  const float4* z4 = (const float4*)(z + (size_t)row * 768);
  const float4* p4 = (const float4*)(prev + (size_t)row * DP);

  float4 v0 = (tid < 192) ? z4[tid] : p4[tid - 192];
  const bool has1 = (tid + 256) < NCH;   // tid < 64
  float4 v1 = make_float4(0.f, 0.f, 0.f, 0.f);
  if (has1) v1 = p4[tid + 64];           // (tid+256)-192
  float s  = v0.x + v0.y + v0.z + v0.w + v1.x + v1.y + v1.z + v1.w;
  float ss = v0.x * v0.x + v0.y * v0.y + v0.z * v0.z + v0.w * v0.w +
             v1.x * v1.x + v1.y * v1.y + v1.z * v1.z + v1.w * v1.w;
#pragma unroll
  for (int off = 32; off > 0; off >>= 1) {
    s += __shfl_down(s, off);
    ss += __shfl_down(ss, off);
  }
  __shared__ float red[10];
  const int wave = tid >> 6, lane = tid & 63;
  if (lane == 0) { red[wave] = s; red[4 + wave] = ss; }
  __syncthreads();
  if (tid == 0) {
    float S = red[0] + red[1] + red[2] + red[3];
    float SS = red[4] + red[5] + red[6] + red[7];
    float mu = S * invD;
    float var = SS * invD - mu * mu;
    red[8] = mu;
    red[9] = rsqrtf(var + 1e-5f);
  }
  __syncthreads();
  const float mu = red[8], rs = red[9];
  {
    const int c = tid;
    float4 g4 = ((const float4*)gam)[c];
    float4 b4 = ((const float4*)bet)[c];
    f16x4 h;
    h[0] = (f16)((v0.x - mu) * rs * g4.x + b4.x);
    h[1] = (f16)((v0.y - mu) * rs * g4.y + b4.y);
    h[2] = (f16)((v0.z - mu) * rs * g4.z + b4.z);
    h[3] = (f16)((v0.w - mu) * rs * g4.w + b4.w);
    ((f16x4*)Xh)[(size_t)row * NCH + c] = h;
    f16x4 r;
    r[0] = (f16)v0.x; r[1] = (f16)v0.y; r[2] = (f16)v0.z; r[3] = (f16)v0.w;
    ((f16x4*)raw)[(size_t)row * NCH + c] = r;
  }
  if (has1) {
    const int c = tid + 256;
    float4 g4 = ((const float4*)gam)[c];
    float4 b4 = ((const float4*)bet)[c];
    f16x4 h;
    h[0] = (f16)((v1.x - mu) * rs * g4.x + b4.x);
    h[1] = (f16)((v1.y - mu) * rs * g4.y + b4.y);
    h[2] = (f16)((v1.z - mu) * rs * g4.z + b4.z);
    h[3] = (f16)((v1.w - mu) * rs * g4.w + b4.w);
    ((f16x4*)Xh)[(size_t)row * NCH + c] = h;
    f16x4 r;
    r[0] = (f16)v1.x; r[1] = (f16)v1.y; r[2] = (f16)v1.z; r[3] = (f16)v1.w;
    ((f16x4*)raw)[(size_t)row * NCH + c] = r;
  }
}

// ---------------- combine(P0..P3[,resid]) + leaky -> lay ; LN([z,lay]) -> Xh ------
// D = 1792 (768 z + 1024 combined). one block per row. P: 4 f16 partials.
template <bool HAS_RESID>
__global__ __launch_bounds__(256) void ln_combine_kernel(
    const float* __restrict__ z, const f16* __restrict__ P,
    float* __restrict__ lay,
    const float* __restrict__ gam, const float* __restrict__ bet,
    f16* __restrict__ Xh) {
  constexpr int DP = 1024, D = 768 + DP, NCH = D / 4;  // 448
  constexpr size_t PSTRIDE = (size_t)4096 * DP;
  constexpr float invD = 1.f / (float)D;
  const int row = blockIdx.x, tid = threadIdx.x;
  const float4* z4 = (const float4*)(z + (size_t)row * 768);
  float4* lay4 = (float4*)(lay + (size_t)row * DP);

  auto comb = [&](int j) -> float4 {
    float4 v = make_float4(0.f, 0.f, 0.f, 0.f);
#pragma unroll
    for (int zz = 0; zz < 4; ++zz) {
      f16x4 a = ((const f16x4*)(P + PSTRIDE * zz + (size_t)row * DP))[j];
      v.x += (float)a[0]; v.y += (float)a[1]; v.z += (float)a[2]; v.w += (float)a[3];
    }
    if constexpr (HAS_RESID) {
      float4 r = lay4[j];
      v.x += r.x; v.y += r.y; v.z += r.z; v.w += r.w;
    }
    v.x = leaky(v.x); v.y = leaky(v.y); v.z = leaky(v.z); v.w = leaky(v.w);
    return v;
  };

  float4 v0, v1;
  if (tid < 192) {
    v0 = z4[tid];
  } else {
    v0 = comb(tid - 192);
  }
  const bool has1 = tid < 192;   // chunk tid+256 valid iff tid+256 < 448
  if (has1) v1 = comb(tid + 64);
  else v1 = make_float4(0.f, 0.f, 0.f, 0.f);

  if (tid >= 192) lay4[tid - 192] = v0;
  if (has1) lay4[tid + 64] = v1;

  float s  = v0.x + v0.y + v0.z + v0.w + v1.x + v1.y + v1.z + v1.w;
  float ss = v0.x * v0.x + v0.y * v0.y + v0.z * v0.z + v0.w * v0.w +
             v1.x * v1.x + v1.y * v1.y + v1.z * v1.z + v1.w * v1.w;
#pragma unroll
  for (int off = 32; off > 0; off >>= 1) {
    s += __shfl_down(s, off);
    ss += __shfl_down(ss, off);
  }
  __shared__ float red[10];
  const int wave = tid >> 6, lane = tid & 63;
  if (lane == 0) { red[wave] = s; red[4 + wave] = ss; }
  __syncthreads();
  if (tid == 0) {
    float S = red[0] + red[1] + red[2] + red[3];
    float SS = red[4] + red[5] + red[6] + red[7];
    float mu = S * invD;
    float var = SS * invD - mu * mu;
    red[8] = mu;
    red[9] = rsqrtf(var + 1e-5f);
  }
  __syncthreads();
  const float mu = red[8], rs = red[9];
  {
    const int c = tid;
    float4 g4 = ((const float4*)gam)[c];
    float4 b4 = ((const float4*)bet)[c];
    f16x4 h;
    h[0] = (f16)((v0.x - mu) * rs * g4.x + b4.x);
    h[1] = (f16)((v0.y - mu) * rs * g4.y + b4.y);
    h[2] = (f16)((v0.z - mu) * rs * g4.z + b4.z);
    h[3] = (f16)((v0.w - mu) * rs * g4.w + b4.w);
    ((f16x4*)Xh)[(size_t)row * NCH + c] = h;
  }
  if (has1) {
    const int c = tid + 256;
    float4 g4 = ((const float4*)gam)[c];
    float4 b4 = ((const float4*)bet)[c];
    f16x4 h;
    h[0] = (f16)((v1.x - mu) * rs * g4.x + b4.x);
    h[1] = (f16)((v1.y - mu) * rs * g4.y + b4.y);
    h[2] = (f16)((v1.z - mu) * rs * g4.z + b4.z);
    h[3] = (f16)((v1.w - mu) * rs * g4.w + b4.w);
    ((f16x4*)Xh)[(size_t)row * NCH + c] = h;
  }
}

// ---------------- final combine: out = P0+P1+P2+P3 (f16 partials -> f32) ----------
__global__ __launch_bounds__(256) void final_combine(const f16* __restrict__ P,
                                                     float* __restrict__ out) {
  constexpr size_t PSTRIDE = (size_t)4096 * 512;
  const int i = blockIdx.x * 256 + threadIdx.x;   // float4 index
  float4 v = make_float4(0.f, 0.f, 0.f, 0.f);
#pragma unroll
  for (int zz = 0; zz < 4; ++zz) {
    f16x4 a = ((const f16x4*)(P + PSTRIDE * zz))[i];
    v.x += (float)a[0]; v.y += (float)a[1]; v.z += (float)a[2]; v.w += (float)a[3];
  }
  ((float4*)out)[i] = v;
}

// ---------------- plain GEMM for gate layers: out = leaky(A @ BT^T + bias), fp16 out
// block tile 128x64, 4 waves (2x2), wave tile 64x32. grid (32, 8). XOR-swizzled LDS.
template <int K>
__global__ __launch_bounds__(256) void gate_gemm(const f16* __restrict__ A,
                                                 const f16* __restrict__ BT,
                                                 const float* __restrict__ bias,
                                                 f16* __restrict__ out) {
  constexpr int N = 512, BK = 64;
  __shared__ f16 sA[128 * BK];
  __shared__ f16 sB[64 * BK];
  const int tid = threadIdx.x, wave = tid >> 6, lane = tid & 63;
  const int quad = lane >> 4, l16 = lane & 15;
  const int wm = (wave >> 1) * 64, wn = (wave & 1) * 32;
  const int row0 = blockIdx.x * 128, col0 = blockIdx.y * 64;
  const int key = (l16 & 7) << 3;

  f32x4 acc[4][2];
#pragma unroll
  for (int ns = 0; ns < 2; ++ns) {
    float bv = bias[col0 + wn + ns * 16 + l16];
    f32x4 b4 = {bv, bv, bv, bv};
#pragma unroll
    for (int ms = 0; ms < 4; ++ms) acc[ms][ns] = b4;
  }
#pragma unroll 1
  for (int k0 = 0; k0 < K; k0 += BK) {
    __syncthreads();
#pragma unroll
    for (int it = 0; it < 4; ++it) {
      int co = ((it * 4 + wave) << 10) | (lane << 4);
      int r = co >> 7;
      int cs = ((((co >> 4) & 7) ^ (r & 7)) << 3);
      gload_lds16(A + (size_t)(row0 + r) * K + (k0 + cs), (char*)sA + co);
    }
#pragma unroll
    for (int it = 0; it < 2; ++it) {
      int co = ((it * 4 + wave) << 10) | (lane << 4);
      int r = co >> 7;
      int cs = ((((co >> 4) & 7) ^ (r & 7)) << 3);
      gload_lds16(BT + (size_t)(col0 + r) * K + (k0 + cs), (char*)sB + co);
    }
    __syncthreads();
#pragma unroll
    for (int kk = 0; kk < BK; kk += 32) {
      f16x8 af[4], bf[2];
#pragma unroll
      for (int ms = 0; ms < 4; ++ms)
        af[ms] = *(const f16x8*)(sA + (wm + ms * 16 + l16) * BK + (((kk + quad * 8)) ^ key));
#pragma unroll
      for (int ns = 0; ns < 2; ++ns)
        bf[ns] = *(const f16x8*)(sB + (wn + ns * 16 + l16) * BK + (((kk + quad * 8)) ^ key));
#pragma unroll
      for (int ms = 0; ms < 4; ++ms)
#pragma unroll
        for (int ns = 0; ns < 2; ++ns)
          acc[ms][ns] = __builtin_amdgcn_mfma_f32_16x16x32_f16(af[ms], bf[ns], acc[ms][ns], 0, 0, 0);
    }
  }
#pragma unroll
  for (int ms = 0; ms < 4; ++ms)
#pragma unroll
    for (int i = 0; i < 4; ++i) {
      const int gr = row0 + wm + ms * 16 + quad * 4 + i;
      f16* op = out + (size_t)gr * N + (col0 + wn + l16);
#pragma unroll
      for (int ns = 0; ns < 2; ++ns) op[ns * 16] = (f16)leaky(acc[ms][ns][i]);
    }
}

// ---------------- gate output layer (512->8) + softmax -> coeff [4096,8] f32 ------
__global__ __launch_bounds__(256) void gate_out_softmax(const f16* __restrict__ g2,
                                                        const float* __restrict__ W,
                                                        const float* __restrict__ bias,
                                                        float* __restrict__ coeff) {
  const int wave = threadIdx.x >> 6, lane = threadIdx.x & 63;
  const int row = blockIdx.x * 4 + wave;
  float acc[8] = {0.f, 0.f, 0.f, 0.f, 0.f, 0.f, 0.f, 0.f};
  const f16* xr = g2 + (size_t)row * 512;
#pragma unroll
  for (int j = 0; j < 8; ++j) {
    int k = lane + 64 * j;
    float x = (float)xr[k];
    const float4* wp = (const float4*)(W + k * 8);
    float4 w0 = wp[0], w1 = wp[1];
    acc[0] += x * w0.x; acc[1] += x * w0.y; acc[2] += x * w0.z; acc[3] += x * w0.w;
    acc[4] += x * w1.x; acc[5] += x * w1.y; acc[6] += x * w1.z; acc[7] += x * w1.w;
  }
#pragma unroll
  for (int off = 32; off > 0; off >>= 1) {
#pragma unroll
    for (int e = 0; e < 8; ++e) acc[e] += __shfl_xor(acc[e], off);
  }
  float m = -1e30f;
#pragma unroll
  for (int e = 0; e < 8; ++e) { acc[e] += bias[e]; m = fmaxf(m, acc[e]); }
  float s = 0.f;
#pragma unroll
  for (int e = 0; e < 8; ++e) { acc[e] = __expf(acc[e] - m); s += acc[e]; }
  const float inv = 1.f / s;
  if (lane == 0) {
    float* cp = coeff + (size_t)row * 8;
#pragma unroll
    for (int e = 0; e < 8; ++e) cp[e] = acc[e] * inv;
  }
}

// ---------------- mixed-expert GEMM, split-K x4 ----------------
// P[z][b,n] = sum_e coeff[b,e] * (X[b, z*K/4:(z+1)*K/4] @ W_e + (z==0)bias_e)[n]
// X: [4096,K] f16, WT: [E,NTOT,K] f16, coeff: [4096,8] f32, P: f16 partials.
// grid (32, NTOT/NB, 4). 4 blocks/CU (LDS 36 KB, VGPR target <=128).
template <int K, int NTOT, int NB>
__global__ __launch_bounds__(256) void mix_gemm(const f16* __restrict__ X,
                                                const f16* __restrict__ WT,
                                                const float* __restrict__ bias,
                                                const float* __restrict__ coeff,
                                                f16* __restrict__ P) {
  constexpr int BK = 64, KH = K / 4;
  constexpr int NSUB = NB / 32;
  constexpr int BISS = (NB * BK * 2) / 4096;
  __shared__ f16 sA[128 * BK];
  __shared__ f16 sB[NB * BK];
  __shared__ float sCoef[128 * 8];

  const int tid = threadIdx.x, wave = tid >> 6, lane = tid & 63;
  const int quad = lane >> 4, l16 = lane & 15;
  const int wm = (wave >> 1) * 64, wn = (wave & 1) * (NB / 2);
  const int row0 = blockIdx.x * 128, col0 = blockIdx.y * NB;
  const int kb = blockIdx.z * KH;
  const int key = (l16 & 7) << 3;

#pragma unroll
  for (int i = tid; i < 128 * 8; i += 256)
    sCoef[i] = coeff[(size_t)(row0 + (i >> 3)) * 8 + (i & 7)];

  f32x4 accM[4][NSUB];
  {
    f32x4 zz = {0.f, 0.f, 0.f, 0.f};
#pragma unroll
    for (int ms = 0; ms < 4; ++ms)
#pragma unroll
      for (int ns = 0; ns < NSUB; ++ns) accM[ms][ns] = zz;
  }

#pragma unroll 1
  for (int e = 0; e < 8; ++e) {
    f32x4 accE[4][NSUB];
#pragma unroll
    for (int ns = 0; ns < NSUB; ++ns) {
      float bv = (blockIdx.z == 0) ? bias[(size_t)e * NTOT + col0 + wn + ns * 16 + l16] : 0.f;
      f32x4 b4 = {bv, bv, bv, bv};
#pragma unroll
      for (int ms = 0; ms < 4; ++ms) accE[ms][ns] = b4;
    }
    const f16* Be = WT + (size_t)e * NTOT * K;
#pragma unroll 1
    for (int k0 = 0; k0 < KH; k0 += BK) {
      __syncthreads();
#pragma unroll
      for (int it = 0; it < 4; ++it) {
        int co = ((it * 4 + wave) << 10) | (lane << 4);
        int r = co >> 7;
        int cs = ((((co >> 4) & 7) ^ (r & 7)) << 3);
        gload_lds16(X + (size_t)(row0 + r) * K + (kb + k0 + cs), (char*)sA + co);
      }
#pragma unroll
      for (int it = 0; it < BISS; ++it) {
        int co = ((it * 4 + wave) << 10) | (lane << 4);
        int r = co >> 7;
        int cs = ((((co >> 4) & 7) ^ (r & 7)) << 3);
        gload_lds16(Be + (size_t)(col0 + r) * K + (kb + k0 + cs), (char*)sB + co);
      }
      __syncthreads();
#pragma unroll
      for (int kk = 0; kk < BK; kk += 32) {
        f16x8 af[4], bf[NSUB];
#pragma unroll
        for (int ms = 0; ms < 4; ++ms)
          af[ms] = *(const f16x8*)(sA + (wm + ms * 16 + l16) * BK + (((kk + quad * 8)) ^ key));
#pragma unroll
        for (int ns = 0; ns < NSUB; ++ns)
          bf[ns] = *(const f16x8*)(sB + (wn + ns * 16 + l16) * BK + (((kk + quad * 8)) ^ key));
#pragma unroll
        for (int ms = 0; ms < 4; ++ms)
#pragma unroll
          for (int ns = 0; ns < NSUB; ++ns)
            accE[ms][ns] = __builtin_amdgcn_mfma_f32_16x16x32_f16(af[ms], bf[ns], accE[ms][ns], 0, 0, 0);
      }
    }
#pragma unroll
    for (int ms = 0; ms < 4; ++ms) {
      const int rb = wm + ms * 16 + quad * 4;
      float c0 = sCoef[(rb + 0) * 8 + e];
      float c1 = sCoef[(rb + 1) * 8 + e];
      float c2 = sCoef[(rb + 2) * 8 + e];
      float c3 = sCoef[(rb + 3) * 8 + e];
#pragma unroll
      for (int ns = 0; ns < NSUB; ++ns) {
        accM[ms][ns][0] += c0 * accE[ms][ns][0];
        accM[ms][ns][1] += c1 * accE[ms][ns][1];
        accM[ms][ns][2] += c2 * accE[ms][ns][2];
        accM[ms][ns][3] += c3 * accE[ms][ns][3];
      }
    }
  }
  f16* Pz = P + (size_t)blockIdx.z * 4096 * NTOT;
#pragma unroll
  for (int ms = 0; ms < 4; ++ms)
#pragma unroll
    for (int i = 0; i < 4; ++i) {
      const int gr = row0 + wm + ms * 16 + quad * 4 + i;
      f16* orow = Pz + (size_t)gr * NTOT + (col0 + wn + l16);
#pragma unroll
      for (int ns = 0; ns < NSUB; ++ns) orow[ns * 16] = (f16)accM[ms][ns][i];
    }
}

// ---------------- launcher ----------------
extern "C" void kernel_launch(void* const* d_in, const int* in_sizes, int n_in,
                              void* d_out, int out_size, void* d_ws, size_t ws_size,
                              hipStream_t stream) {
  const float* z = (const float*)d_in[0];
  const float* c = (const float*)d_in[1];
  const float* w[5]   = {(const float*)d_in[2], (const float*)d_in[6], (const float*)d_in[10],
                         (const float*)d_in[14], (const float*)d_in[18]};
  const float* bb[5]  = {(const float*)d_in[3], (const float*)d_in[7], (const float*)d_in[11],
                         (const float*)d_in[15], (const float*)d_in[19]};
  const float* lng[5] = {(const float*)d_in[4], (const float*)d_in[8], (const float*)d_in[12],
                         (const float*)d_in[16], (const float*)d_in[20]};
  const float* lnb[5] = {(const float*)d_in[5], (const float*)d_in[9], (const float*)d_in[13],
                         (const float*)d_in[17], (const float*)d_in[21]};
  const float* gW0 = (const float*)d_in[22];
  const float* gb0 = (const float*)d_in[23];
  const float* gW1 = (const float*)d_in[24];
  const float* gb1 = (const float*)d_in[25];
  const float* gW2 = (const float*)d_in[26];
  const float* gb2 = (const float*)d_in[27];
  float* outF = (float*)d_out;

  // workspace layout (~96.3 MB). P (4 x f16 partials) aliases the dead gate bufs.
  char* ws = (char*)d_ws;
  f16*   WT    = (f16*)(ws + 0);               // 29,360,128
  f16*   gT0   = (f16*)(ws + 29360128);        //  1,310,720
  f16*   gT1   = (f16*)(ws + 30670848);        //    524,288
  f16*   Xh    = (f16*)(ws + 31195136);        // 14,680,064
  float* coeff = (float*)(ws + 45875200);      //    131,072
  float* lay   = (float*)(ws + 46006272);      // 16,777,216
  // union region @62,783,488 (33,554,432 B): gate bufs then P0..P3 (f16)
  f16*   zc_h  = (f16*)(ws + 62783488);        // 10,485,760
  f16*   g1h   = (f16*)(ws + 73269248);        //  4,194,304
  f16*   g2h   = (f16*)(ws + 77463552);        //  4,194,304
  f16*   P     = (f16*)(ws + 62783488);        // 4 x 4096*1024*2 = 33,554,432

  const dim3 tb(32, 8, 1);

  // gate weight transposes (f32 -> f16, [K,N] -> [N,K])
  transpose_cast<<<dim3(16, 40, 1), tb, 0, stream>>>(gW0, gT0, 1280, 512);
  transpose_cast<<<dim3(16, 16, 1), tb, 0, stream>>>(gW1, gT1, 512, 512);

  // LN0 -> Xh[,1280]; raw fp16 concat -> zc_h
  ln0_kernel<<<4096, 256, 0, stream>>>(z, c, lng[0], lnb[0], Xh, zc_h);

  // gate MLP -> coeff
  gate_gemm<1280><<<dim3(32, 8), 256, 0, stream>>>(zc_h, gT0, gb0, g1h);
  gate_gemm<512><<<dim3(32, 8), 256, 0, stream>>>(g1h, gT1, gb1, g2h);
  gate_out_softmax<<<1024, 256, 0, stream>>>(g2h, gW2, gb2, coeff);

  // layer 0 (gate bufs dead from here; P may alias them)
  transpose_cast<<<dim3(32, 40, 8), tb, 0, stream>>>(w[0], WT, 1280, 1024);
  mix_gemm<1280, 1024, 128><<<dim3(32, 8, 4), 256, 0, stream>>>(Xh, WT, bb[0], coeff, P);
  ln_combine_kernel<false><<<4096, 256, 0, stream>>>(z, P, lay, lng[1], lnb[1], Xh);

  // layers 1..3
  for (int i = 1; i <= 3; ++i) {
    transpose_cast<<<dim3(32, 56, 8), tb, 0, stream>>>(w[i], WT, 1792, 1024);
    mix_gemm<1792, 1024, 128><<<dim3(32, 8, 4), 256, 0, stream>>>(Xh, WT, bb[i], coeff, P);
    const int nl = (i < 3) ? i + 1 : 4;
    ln_combine_kernel<true><<<4096, 256, 0, stream>>>(z, P, lay, lng[nl], lnb[nl], Xh);
  }

  // layer 4: out = sum of 4 partials (no activation, no residual)
  transpose_cast<<<dim3(16, 56, 8), tb, 0, stream>>>(w[4], WT, 1792, 512);
  mix_gemm<1792, 512, 64><<<dim3(32, 8, 4), 256, 0, stream>>>(Xh, WT, bb[4], coeff, P);
  final_combine<<<2048, 256, 0, stream>>>(P, outF);

  (void)in_sizes; (void)n_in; (void)out_size; (void)ws_size;
}

// Round 5
// 955.120 us; speedup vs baseline: 1.1884x; 1.1884x over previous
//
#include <hip/hip_runtime.h>

// GatingMixedDecoder: B=4096, LATENT=768, COND=512, INPUT=1280, HIDDEN=1024,
// OUT=512, E=8, GATE_H=512, INTER=1792.
// fp16 MFMA (16x16x32) for all GEMMs, fp32 elsewhere.
// R5: restructured mix_gemm K-loop: k0-outer / expert-inner, A staged once per
//     k0 (af held in regs), A-fragment prescaled by coeff (f16) -> single accM
//     accumulator (saves 64 AGPRs -> 3 blocks/CU), B double-buffered with one
//     barrier per e-step (prefetch issued after barrier, consumed after next).
//     Bias mixed in epilogue from LDS tiles. Split-K x2, f16 partials.

typedef _Float16 f16;
typedef _Float16 f16x8 __attribute__((ext_vector_type(8)));
typedef _Float16 f16x4 __attribute__((ext_vector_type(4)));
typedef float    f32x4 __attribute__((ext_vector_type(4)));

typedef __attribute__((address_space(1))) void as1_void;
typedef __attribute__((address_space(3))) void as3_void;

__device__ __forceinline__ void gload_lds16(const void* g, void* l) {
  __builtin_amdgcn_global_load_lds((as1_void*)g, (as3_void*)l, 16, 0, 0);
}

__device__ __forceinline__ float leaky(float v) { return v > 0.f ? v : 0.01f * v; }

// ---------------- transpose + cast f32 -> f16 ----------------
__global__ __launch_bounds__(256) void transpose_cast(const float* __restrict__ in,
                                                      f16* __restrict__ out,
                                                      int R, int C) {
  __shared__ float tile[32][33];
  const size_t mat = (size_t)R * C;
  const float* I = in + mat * blockIdx.z;
  f16* O = out + mat * blockIdx.z;
  const int c0 = blockIdx.x * 32, r0 = blockIdx.y * 32;
  const int tx = threadIdx.x, ty = threadIdx.y;
#pragma unroll
  for (int i = ty; i < 32; i += 8)
    tile[i][tx] = I[(size_t)(r0 + i) * C + (c0 + tx)];
  __syncthreads();
#pragma unroll
  for (int i = ty; i < 32; i += 8)
    O[(size_t)(c0 + i) * R + (r0 + tx)] = (f16)tile[tx][i];
}

// ---------------- LN0 over concat(z[768], c[512]) -> fp16 Xh; raw fp16 -> zc_h ----
__global__ __launch_bounds__(256) void ln0_kernel(
    const float* __restrict__ z, const float* __restrict__ prev,
    const float* __restrict__ gam, const float* __restrict__ bet,
    f16* __restrict__ Xh, f16* __restrict__ raw) {
  constexpr int DP = 512, D = 768 + DP, NCH = D / 4;  // 320
  constexpr float invD = 1.f / (float)D;
  const int row = blockIdx.x, tid = threadIdx.x;
  const float4* z4 = (const float4*)(z + (size_t)row * 768);
  const float4* p4 = (const float4*)(prev + (size_t)row * DP);

  float4 v0 = (tid < 192) ? z4[tid] : p4[tid - 192];
  const bool has1 = (tid + 256) < NCH;   // tid < 64
  float4 v1 = make_float4(0.f, 0.f, 0.f, 0.f);
  if (has1) v1 = p4[tid + 64];
  float s  = v0.x + v0.y + v0.z + v0.w + v1.x + v1.y + v1.z + v1.w;
  float ss = v0.x * v0.x + v0.y * v0.y + v0.z * v0.z + v0.w * v0.w +
             v1.x * v1.x + v1.y * v1.y + v1.z * v1.z + v1.w * v1.w;
#pragma unroll
  for (int off = 32; off > 0; off >>= 1) {
    s += __shfl_down(s, off);
    ss += __shfl_down(ss, off);
  }
  __shared__ float red[10];
  const int wave = tid >> 6, lane = tid & 63;
  if (lane == 0) { red[wave] = s; red[4 + wave] = ss; }
  __syncthreads();
  if (tid == 0) {
    float S = red[0] + red[1] + red[2] + red[3];
    float SS = red[4] + red[5] + red[6] + red[7];
    float mu = S * invD;
    float var = SS * invD - mu * mu;
    red[8] = mu;
    red[9] = rsqrtf(var + 1e-5f);
  }
  __syncthreads();
  const float mu = red[8], rs = red[9];
  {
    const int c = tid;
    float4 g4 = ((const float4*)gam)[c];
    float4 b4 = ((const float4*)bet)[c];
    f16x4 h;
    h[0] = (f16)((v0.x - mu) * rs * g4.x + b4.x);
    h[1] = (f16)((v0.y - mu) * rs * g4.y + b4.y);
    h[2] = (f16)((v0.z - mu) * rs * g4.z + b4.z);
    h[3] = (f16)((v0.w - mu) * rs * g4.w + b4.w);
    ((f16x4*)Xh)[(size_t)row * NCH + c] = h;
    f16x4 r;
    r[0] = (f16)v0.x; r[1] = (f16)v0.y; r[2] = (f16)v0.z; r[3] = (f16)v0.w;
    ((f16x4*)raw)[(size_t)row * NCH + c] = r;
  }
  if (has1) {
    const int c = tid + 256;
    float4 g4 = ((const float4*)gam)[c];
    float4 b4 = ((const float4*)bet)[c];
    f16x4 h;
    h[0] = (f16)((v1.x - mu) * rs * g4.x + b4.x);
    h[1] = (f16)((v1.y - mu) * rs * g4.y + b4.y);
    h[2] = (f16)((v1.z - mu) * rs * g4.z + b4.z);
    h[3] = (f16)((v1.w - mu) * rs * g4.w + b4.w);
    ((f16x4*)Xh)[(size_t)row * NCH + c] = h;
    f16x4 r;
    r[0] = (f16)v1.x; r[1] = (f16)v1.y; r[2] = (f16)v1.z; r[3] = (f16)v1.w;
    ((f16x4*)raw)[(size_t)row * NCH + c] = r;
  }
}

// ---------------- combine(P0,P1[,resid]) + leaky -> lay ; LN([z,lay]) -> Xh -------
// D = 1792 (768 z + 1024 combined). one block per row. P: 2 f16 partials.
template <bool HAS_RESID>
__global__ __launch_bounds__(256) void ln_combine_kernel(
    const float* __restrict__ z, const f16* __restrict__ P,
    float* __restrict__ lay,
    const float* __restrict__ gam, const float* __restrict__ bet,
    f16* __restrict__ Xh) {
  constexpr int DP = 1024, D = 768 + DP, NCH = D / 4;  // 448
  constexpr size_t PSTRIDE = (size_t)4096 * DP;
  constexpr float invD = 1.f / (float)D;
  const int row = blockIdx.x, tid = threadIdx.x;
  const float4* z4 = (const float4*)(z + (size_t)row * 768);
  float4* lay4 = (float4*)(lay + (size_t)row * DP);

  auto comb = [&](int j) -> float4 {
    float4 v = make_float4(0.f, 0.f, 0.f, 0.f);
#pragma unroll
    for (int zz = 0; zz < 2; ++zz) {
      f16x4 a = ((const f16x4*)(P + PSTRIDE * zz + (size_t)row * DP))[j];
      v.x += (float)a[0]; v.y += (float)a[1]; v.z += (float)a[2]; v.w += (float)a[3];
    }
    if constexpr (HAS_RESID) {
      float4 r = lay4[j];
      v.x += r.x; v.y += r.y; v.z += r.z; v.w += r.w;
    }
    v.x = leaky(v.x); v.y = leaky(v.y); v.z = leaky(v.z); v.w = leaky(v.w);
    return v;
  };

  float4 v0, v1;
  if (tid < 192) {
    v0 = z4[tid];
  } else {
    v0 = comb(tid - 192);
  }
  const bool has1 = tid < 192;
  if (has1) v1 = comb(tid + 64);
  else v1 = make_float4(0.f, 0.f, 0.f, 0.f);

  if (tid >= 192) lay4[tid - 192] = v0;
  if (has1) lay4[tid + 64] = v1;

  float s  = v0.x + v0.y + v0.z + v0.w + v1.x + v1.y + v1.z + v1.w;
  float ss = v0.x * v0.x + v0.y * v0.y + v0.z * v0.z + v0.w * v0.w +
             v1.x * v1.x + v1.y * v1.y + v1.z * v1.z + v1.w * v1.w;
#pragma unroll
  for (int off = 32; off > 0; off >>= 1) {
    s += __shfl_down(s, off);
    ss += __shfl_down(ss, off);
  }
  __shared__ float red[10];
  const int wave = tid >> 6, lane = tid & 63;
  if (lane == 0) { red[wave] = s; red[4 + wave] = ss; }
  __syncthreads();
  if (tid == 0) {
    float S = red[0] + red[1] + red[2] + red[3];
    float SS = red[4] + red[5] + red[6] + red[7];
    float mu = S * invD;
    float var = SS * invD - mu * mu;
    red[8] = mu;
    red[9] = rsqrtf(var + 1e-5f);
  }
  __syncthreads();
  const float mu = red[8], rs = red[9];
  {
    const int c = tid;
    float4 g4 = ((const float4*)gam)[c];
    float4 b4 = ((const float4*)bet)[c];
    f16x4 h;
    h[0] = (f16)((v0.x - mu) * rs * g4.x + b4.x);
    h[1] = (f16)((v0.y - mu) * rs * g4.y + b4.y);
    h[2] = (f16)((v0.z - mu) * rs * g4.z + b4.z);
    h[3] = (f16)((v0.w - mu) * rs * g4.w + b4.w);
    ((f16x4*)Xh)[(size_t)row * NCH + c] = h;
  }
  if (has1) {
    const int c = tid + 256;
    float4 g4 = ((const float4*)gam)[c];
    float4 b4 = ((const float4*)bet)[c];
    f16x4 h;
    h[0] = (f16)((v1.x - mu) * rs * g4.x + b4.x);
    h[1] = (f16)((v1.y - mu) * rs * g4.y + b4.y);
    h[2] = (f16)((v1.z - mu) * rs * g4.z + b4.z);
    h[3] = (f16)((v1.w - mu) * rs * g4.w + b4.w);
    ((f16x4*)Xh)[(size_t)row * NCH + c] = h;
  }
}

// ---------------- final combine: out = P0 + P1 (f16 partials -> f32) --------------
__global__ __launch_bounds__(256) void final_combine(const f16* __restrict__ P,
                                                     float* __restrict__ out) {
  constexpr size_t PSTRIDE = (size_t)4096 * 512;
  const int i = blockIdx.x * 256 + threadIdx.x;   // float4 index
  float4 v = make_float4(0.f, 0.f, 0.f, 0.f);
#pragma unroll
  for (int zz = 0; zz < 2; ++zz) {
    f16x4 a = ((const f16x4*)(P + PSTRIDE * zz))[i];
    v.x += (float)a[0]; v.y += (float)a[1]; v.z += (float)a[2]; v.w += (float)a[3];
  }
  ((float4*)out)[i] = v;
}

// ---------------- plain GEMM for gate layers (unchanged from R3) ----------------
template <int K>
__global__ __launch_bounds__(256) void gate_gemm(const f16* __restrict__ A,
                                                 const f16* __restrict__ BT,
                                                 const float* __restrict__ bias,
                                                 f16* __restrict__ out) {
  constexpr int N = 512, BK = 64;
  __shared__ f16 sA[128 * BK];
  __shared__ f16 sB[64 * BK];
  const int tid = threadIdx.x, wave = tid >> 6, lane = tid & 63;
  const int quad = lane >> 4, l16 = lane & 15;
  const int wm = (wave >> 1) * 64, wn = (wave & 1) * 32;
  const int row0 = blockIdx.x * 128, col0 = blockIdx.y * 64;
  const int key = (l16 & 7) << 3;

  f32x4 acc[4][2];
#pragma unroll
  for (int ns = 0; ns < 2; ++ns) {
    float bv = bias[col0 + wn + ns * 16 + l16];
    f32x4 b4 = {bv, bv, bv, bv};
#pragma unroll
    for (int ms = 0; ms < 4; ++ms) acc[ms][ns] = b4;
  }
#pragma unroll 1
  for (int k0 = 0; k0 < K; k0 += BK) {
    __syncthreads();
#pragma unroll
    for (int it = 0; it < 4; ++it) {
      int co = ((it * 4 + wave) << 10) | (lane << 4);
      int r = co >> 7;
      int cs = ((((co >> 4) & 7) ^ (r & 7)) << 3);
      gload_lds16(A + (size_t)(row0 + r) * K + (k0 + cs), (char*)sA + co);
    }
#pragma unroll
    for (int it = 0; it < 2; ++it) {
      int co = ((it * 4 + wave) << 10) | (lane << 4);
      int r = co >> 7;
      int cs = ((((co >> 4) & 7) ^ (r & 7)) << 3);
      gload_lds16(BT + (size_t)(col0 + r) * K + (k0 + cs), (char*)sB + co);
    }
    __syncthreads();
#pragma unroll
    for (int kk = 0; kk < BK; kk += 32) {
      f16x8 af[4], bf[2];
#pragma unroll
      for (int ms = 0; ms < 4; ++ms)
        af[ms] = *(const f16x8*)(sA + (wm + ms * 16 + l16) * BK + (((kk + quad * 8)) ^ key));
#pragma unroll
      for (int ns = 0; ns < 2; ++ns)
        bf[ns] = *(const f16x8*)(sB + (wn + ns * 16 + l16) * BK + (((kk + quad * 8)) ^ key));
#pragma unroll
      for (int ms = 0; ms < 4; ++ms)
#pragma unroll
        for (int ns = 0; ns < 2; ++ns)
          acc[ms][ns] = __builtin_amdgcn_mfma_f32_16x16x32_f16(af[ms], bf[ns], acc[ms][ns], 0, 0, 0);
    }
  }
#pragma unroll
  for (int ms = 0; ms < 4; ++ms)
#pragma unroll
    for (int i = 0; i < 4; ++i) {
      const int gr = row0 + wm + ms * 16 + quad * 4 + i;
      f16* op = out + (size_t)gr * N + (col0 + wn + l16);
#pragma unroll
      for (int ns = 0; ns < 2; ++ns) op[ns * 16] = (f16)leaky(acc[ms][ns][i]);
    }
}

// ---------------- gate output layer (512->8) + softmax -> coeff [4096,8] f32 ------
__global__ __launch_bounds__(256) void gate_out_softmax(const f16* __restrict__ g2,
                                                        const float* __restrict__ W,
                                                        const float* __restrict__ bias,
                                                        float* __restrict__ coeff) {
  const int wave = threadIdx.x >> 6, lane = threadIdx.x & 63;
  const int row = blockIdx.x * 4 + wave;
  float acc[8] = {0.f, 0.f, 0.f, 0.f, 0.f, 0.f, 0.f, 0.f};
  const f16* xr = g2 + (size_t)row * 512;
#pragma unroll
  for (int j = 0; j < 8; ++j) {
    int k = lane + 64 * j;
    float x = (float)xr[k];
    const float4* wp = (const float4*)(W + k * 8);
    float4 w0 = wp[0], w1 = wp[1];
    acc[0] += x * w0.x; acc[1] += x * w0.y; acc[2] += x * w0.z; acc[3] += x * w0.w;
    acc[4] += x * w1.x; acc[5] += x * w1.y; acc[6] += x * w1.z; acc[7] += x * w1.w;
  }
#pragma unroll
  for (int off = 32; off > 0; off >>= 1) {
#pragma unroll
    for (int e = 0; e < 8; ++e) acc[e] += __shfl_xor(acc[e], off);
  }
  float m = -1e30f;
#pragma unroll
  for (int e = 0; e < 8; ++e) { acc[e] += bias[e]; m = fmaxf(m, acc[e]); }
  float s = 0.f;
#pragma unroll
  for (int e = 0; e < 8; ++e) { acc[e] = __expf(acc[e] - m); s += acc[e]; }
  const float inv = 1.f / s;
  if (lane == 0) {
    float* cp = coeff + (size_t)row * 8;
#pragma unroll
    for (int e = 0; e < 8; ++e) cp[e] = acc[e] * inv;
  }
}

// ---------------- mixed-expert GEMM, restructured K-loop ----------------
// P[z][b,n] = sum_e coeff[b,e] * (X[b, z*KH:(z+1)*KH] @ W_e)[n]  (+coeff@bias on z==0)
// k0-outer / expert-inner. A staged once per k0 (af in regs across the e-loop).
// A-fragment prescaled by coeff (f16) -> single accM accumulator.
// B double-buffered, ONE barrier per e-step; prefetch B(e+1) issued right after
// the barrier, consumed after the next barrier (drain overlaps 32 MFMA).
// grid (32, NTOT/NB, 2).
template <int K, int NTOT, int NB>
__global__ __launch_bounds__(256) void mix_gemm(const f16* __restrict__ X,
                                                const f16* __restrict__ WT,
                                                const float* __restrict__ bias,
                                                const float* __restrict__ coeff,
                                                f16* __restrict__ P) {
  constexpr int BK = 64, KH = K / 2;
  constexpr int NSUB = NB / 32;
  constexpr int BISS = (NB * BK * 2) / 4096;
  __shared__ f16 sA[128 * BK];
  __shared__ f16 sB[2][NB * BK];
  __shared__ f16 sCoefH[128 * 8];
  __shared__ f16 sBiasH[8 * NB];

  const int tid = threadIdx.x, wave = tid >> 6, lane = tid & 63;
  const int quad = lane >> 4, l16 = lane & 15;
  const int wm = (wave >> 1) * 64, wn = (wave & 1) * (NB / 2);
  const int row0 = blockIdx.x * 128, col0 = blockIdx.y * NB;
  const int kb = blockIdx.z * KH;
  const int key = (l16 & 7) << 3;

  for (int i = tid; i < 128 * 8; i += 256)
    sCoefH[i] = (f16)coeff[(size_t)(row0 + (i >> 3)) * 8 + (i & 7)];
  for (int i = tid; i < 8 * NB; i += 256)
    sBiasH[i] = (f16)bias[(size_t)(i / NB) * NTOT + col0 + (i % NB)];

  auto stageA = [&](int k0) {
#pragma unroll
    for (int it = 0; it < 4; ++it) {
      int co = ((it * 4 + wave) << 10) | (lane << 4);
      int r = co >> 7;
      int cs = ((((co >> 4) & 7) ^ (r & 7)) << 3);
      gload_lds16(X + (size_t)(row0 + r) * K + (kb + k0 + cs), (char*)sA + co);
    }
  };
  auto stageB = [&](int e, int k0, int b) {
    const f16* Be = WT + (size_t)e * NTOT * K;
#pragma unroll
    for (int it = 0; it < BISS; ++it) {
      int co = ((it * 4 + wave) << 10) | (lane << 4);
      int r = co >> 7;
      int cs = ((((co >> 4) & 7) ^ (r & 7)) << 3);
      gload_lds16(Be + (size_t)(col0 + r) * K + (kb + k0 + cs), (char*)sB[b] + co);
    }
  };

  f32x4 accM[4][NSUB];
  {
    f32x4 zz = {0.f, 0.f, 0.f, 0.f};
#pragma unroll
    for (int ms = 0; ms < 4; ++ms)
#pragma unroll
      for (int ns = 0; ns < NSUB; ++ns) accM[ms][ns] = zz;
  }

  f16x8 af[2][4];
  stageA(0);
  stageB(0, 0, 0);
  int buf = 0;

#pragma unroll 1
  for (int k0 = 0; k0 < KH; k0 += BK) {
#pragma unroll 1
    for (int e = 0; e < 8; ++e) {
      __syncthreads();   // drains the prefetch issued LAST e-step + all LDS reads
      // issue next prefetch (consumed after the NEXT barrier)
      if (e < 7)                stageB(e + 1, k0, buf ^ 1);
      else if (k0 + BK < KH)    stageB(0, k0 + BK, buf ^ 1);
      if (e == 1 && k0 + BK < KH) stageA(k0 + BK);  // af regs were read at e==0
      if (e == 0) {
#pragma unroll
        for (int kk = 0; kk < 2; ++kk)
#pragma unroll
          for (int ms = 0; ms < 4; ++ms)
            af[kk][ms] = *(const f16x8*)(sA + (wm + ms * 16 + l16) * BK +
                                         ((kk * 32 + quad * 8) ^ key));
      }
      // per-expert coeff for this wave's A-rows (A-operand row = l16)
      f16 ce[4];
#pragma unroll
      for (int ms = 0; ms < 4; ++ms)
        ce[ms] = sCoefH[(wm + ms * 16 + l16) * 8 + e];
#pragma unroll
      for (int kk = 0; kk < 2; ++kk) {
        f16x8 bf[NSUB];
#pragma unroll
        for (int ns = 0; ns < NSUB; ++ns)
          bf[ns] = *(const f16x8*)(sB[buf] + (wn + ns * 16 + l16) * BK +
                                   ((kk * 32 + quad * 8) ^ key));
#pragma unroll
        for (int ms = 0; ms < 4; ++ms) {
          f16x8 as;
#pragma unroll
          for (int j = 0; j < 8; ++j) as[j] = af[kk][ms][j] * ce[ms];
#pragma unroll
          for (int ns = 0; ns < NSUB; ++ns)
            accM[ms][ns] = __builtin_amdgcn_mfma_f32_16x16x32_f16(as, bf[ns], accM[ms][ns], 0, 0, 0);
        }
      }
      buf ^= 1;
    }
  }

  // epilogue: add coeff-mixed bias (z==0 only), store f16 partial
  const bool addB = (blockIdx.z == 0);
  f16* Pz = P + (size_t)blockIdx.z * 4096 * NTOT;
#pragma unroll
  for (int ms = 0; ms < 4; ++ms)
#pragma unroll
    for (int i = 0; i < 4; ++i) {
      const int lr = wm + ms * 16 + quad * 4 + i;   // local row
      const int gr = row0 + lr;
      f16x8 ch = *(const f16x8*)(sCoefH + lr * 8);
      f16* orow = Pz + (size_t)gr * NTOT + (col0 + wn + l16);
#pragma unroll
      for (int ns = 0; ns < NSUB; ++ns) {
        float v = accM[ms][ns][i];
        if (addB) {
          float bsum = 0.f;
#pragma unroll
          for (int e = 0; e < 8; ++e)
            bsum += (float)ch[e] * (float)sBiasH[e * NB + wn + ns * 16 + l16];
          v += bsum;
        }
        orow[ns * 16] = (f16)v;
      }
    }
}

// ---------------- launcher ----------------
extern "C" void kernel_launch(void* const* d_in, const int* in_sizes, int n_in,
                              void* d_out, int out_size, void* d_ws, size_t ws_size,
                              hipStream_t stream) {
  const float* z = (const float*)d_in[0];
  const float* c = (const float*)d_in[1];
  const float* w[5]   = {(const float*)d_in[2], (const float*)d_in[6], (const float*)d_in[10],
                         (const float*)d_in[14], (const float*)d_in[18]};
  const float* bb[5]  = {(const float*)d_in[3], (const float*)d_in[7], (const float*)d_in[11],
                         (const float*)d_in[15], (const float*)d_in[19]};
  const float* lng[5] = {(const float*)d_in[4], (const float*)d_in[8], (const float*)d_in[12],
                         (const float*)d_in[16], (const float*)d_in[20]};
  const float* lnb[5] = {(const float*)d_in[5], (const float*)d_in[9], (const float*)d_in[13],
                         (const float*)d_in[17], (const float*)d_in[21]};
  const float* gW0 = (const float*)d_in[22];
  const float* gb0 = (const float*)d_in[23];
  const float* gW1 = (const float*)d_in[24];
  const float* gb1 = (const float*)d_in[25];
  const float* gW2 = (const float*)d_in[26];
  const float* gb2 = (const float*)d_in[27];
  float* outF = (float*)d_out;

  // workspace layout (~96.3 MB). P (2 x f16 partials) aliases dead gate bufs.
  char* ws = (char*)d_ws;
  f16*   WT    = (f16*)(ws + 0);               // 29,360,128
  f16*   gT0   = (f16*)(ws + 29360128);        //  1,310,720
  f16*   gT1   = (f16*)(ws + 30670848);        //    524,288
  f16*   Xh    = (f16*)(ws + 31195136);        // 14,680,064
  float* coeff = (float*)(ws + 45875200);      //    131,072
  float* lay   = (float*)(ws + 46006272);      // 16,777,216
  // union region @62,783,488 (33,554,432 B): gate bufs then P0/P1 (f16)
  f16*   zc_h  = (f16*)(ws + 62783488);        // 10,485,760
  f16*   g1h   = (f16*)(ws + 73269248);        //  4,194,304
  f16*   g2h   = (f16*)(ws + 77463552);        //  4,194,304
  f16*   P     = (f16*)(ws + 62783488);        // 2 x 4096*1024*2 = 16,777,216

  const dim3 tb(32, 8, 1);

  // gate weight transposes (f32 -> f16, [K,N] -> [N,K])
  transpose_cast<<<dim3(16, 40, 1), tb, 0, stream>>>(gW0, gT0, 1280, 512);
  transpose_cast<<<dim3(16, 16, 1), tb, 0, stream>>>(gW1, gT1, 512, 512);

  // LN0 -> Xh[,1280]; raw fp16 concat -> zc_h
  ln0_kernel<<<4096, 256, 0, stream>>>(z, c, lng[0], lnb[0], Xh, zc_h);

  // gate MLP -> coeff
  gate_gemm<1280><<<dim3(32, 8), 256, 0, stream>>>(zc_h, gT0, gb0, g1h);
  gate_gemm<512><<<dim3(32, 8), 256, 0, stream>>>(g1h, gT1, gb1, g2h);
  gate_out_softmax<<<1024, 256, 0, stream>>>(g2h, gW2, gb2, coeff);

  // layer 0 (gate bufs dead from here; P may alias them)
  transpose_cast<<<dim3(32, 40, 8), tb, 0, stream>>>(w[0], WT, 1280, 1024);
  mix_gemm<1280, 1024, 128><<<dim3(32, 8, 2), 256, 0, stream>>>(Xh, WT, bb[0], coeff, P);
  ln_combine_kernel<false><<<4096, 256, 0, stream>>>(z, P, lay, lng[1], lnb[1], Xh);

  // layers 1..3
  for (int i = 1; i <= 3; ++i) {
    transpose_cast<<<dim3(32, 56, 8), tb, 0, stream>>>(w[i], WT, 1792, 1024);
    mix_gemm<1792, 1024, 128><<<dim3(32, 8, 2), 256, 0, stream>>>(Xh, WT, bb[i], coeff, P);
    const int nl = (i < 3) ? i + 1 : 4;
    ln_combine_kernel<true><<<4096, 256, 0, stream>>>(z, P, lay, lng[nl], lnb[nl], Xh);
  }

  // layer 4: out = P0 + P1 (no activation, no residual)
  transpose_cast<<<dim3(16, 56, 8), tb, 0, stream>>>(w[4], WT, 1792, 512);
  mix_gemm<1792, 512, 64><<<dim3(32, 8, 2), 256, 0, stream>>>(Xh, WT, bb[4], coeff, P);
  final_combine<<<2048, 256, 0, stream>>>(P, outF);

  (void)in_sizes; (void)n_in; (void)out_size; (void)ws_size;
}